// Round 16
// baseline (62.292 us; speedup 1.0000x reference)
//
#include <hip/hip_runtime.h>
#include <stdint.h>
#include <stddef.h>

// MMD loss, fused: gram = X·X^T (bf16 MFMA) + 5-kernel RBF epilogue + signed mean.
// N=8192 rows (4096 src + 4096 tgt), D=256.
//
// Round-16: LDS-ELIMINATION experiment at constant residency.
//  Evidence: R14 (deeper prefetch)=0, R15 (2x TLP)=WORSE, R5 (locality)=0 ->
//  contention-limited; remaining untested axis is the LDS pipe: R13 funnels
//  all A-fragments through LDS (8 waves x 32 ds_read_b128/tile @ ~12cyc on
//  the single per-CU LDS unit + 64KB staging + barriers). NEW: A read DIRECT
//  from L2 via the fragment layout with a 2-deep A-ring + 4-deep B-ring
//  (R13's proven prefetch discipline), NO LDS, NO in-loop barriers; (256,2)
//  caps via VGPR at the same 2 blocks/CU -> isolates the LDS variable.
//  Also: bw_kernel 256->1024 threads (was a serial 1-block ~5us kernel).
//  Kept: zero device-scope serialization, plain-store partials, 512 blocks x
//  4-5 consecutive tiles, XCD swizzle, fragment-transposed Xbt.
//
// Fragment layout: elem(r,k) at (r>>4)*4096 + (k>>3)*128 + (r&15)*8 + (k&7)
// -> lane(lo,hi) fragment base byte = rowgroup*8192 + (kc*4+hi)*256 + lo*16
//    (contiguous 1KB per wave per fragment load).
//
// ws layout:
//   [0]      float  coef            (-log2(e)/(16*bandwidth))
//   [64]     double partial[512]    -> [64, 4160)
//   [16704]  float  csp[256*256]    -> [16704, 278848)
//   [278848] float  sq[8192]        -> [278848, 311616)
//   [311616] ushort Xbt[8192*256]   (bf16, fragment-transposed, 4MB)

#define N_TOT 8192
#define D_DIM 256
#define BS    4096
#define NB    64      // 128-row tiles per dim
#define NTILE 2080    // upper-tri 128x128 tiles
#define NBLK  512     // blocks: 32 x 5 tiles + 480 x 4 tiles = 2080 (% 8 == 0)

typedef float  f32x4  __attribute__((ext_vector_type(4)));
typedef short  bf16x8 __attribute__((ext_vector_type(8)));

__device__ __forceinline__ unsigned short f2bf(float f) {
  unsigned u = __float_as_uint(f);
  u += 0x7fffu + ((u >> 16) & 1u);   // RNE; inputs are finite
  return (unsigned short)(u >> 16);
}
__device__ __forceinline__ float bf2f(unsigned short s) {
  return __uint_as_float(((unsigned)s) << 16);
}

// ---- prep: f32 -> bf16 fragment-transposed copy + row sq-norms + column partials ----
// 256 blocks x 512 threads; 32 rows/block, 4 rows/wave.
__global__ void prep_kernel(const float* __restrict__ src, const float* __restrict__ tgt,
                            unsigned short* __restrict__ Xbt, float* __restrict__ sq,
                            float* __restrict__ csp) {
  int tid  = threadIdx.x;
  int w    = tid >> 6, lane = tid & 63;
  int blk  = blockIdx.x;
  float4 cacc = {0.f, 0.f, 0.f, 0.f};

  #pragma unroll
  for (int r = 0; r < 4; ++r) {
    int row = blk * 32 + w * 4 + r;
    const float* rowp = (row < BS) ? (src + (size_t)row * D_DIM)
                                   : (tgt + (size_t)(row - BS) * D_DIM);
    float4 v = reinterpret_cast<const float4*>(rowp)[lane];   // cols k..k+3, k=lane*4
    cacc.x += v.x; cacc.y += v.y; cacc.z += v.z; cacc.w += v.w;
    ushort4 b;
    b.x = f2bf(v.x); b.y = f2bf(v.y); b.z = f2bf(v.z); b.w = f2bf(v.w);
    int k = lane * 4;
    size_t off = ((size_t)(row >> 4)) * 4096 + (size_t)(k >> 3) * 128
               + (size_t)((row & 15) * 8) + (k & 7);
    *reinterpret_cast<ushort4*>(Xbt + off) = b;
    float fx = bf2f(b.x), fy = bf2f(b.y), fz = bf2f(b.z), fw = bf2f(b.w);
    float s = fx * fx + fy * fy + fz * fz + fw * fw;
    #pragma unroll
    for (int o = 32; o; o >>= 1) s += __shfl_down(s, o, 64);
    if (lane == 0) sq[row] = s;
  }

  __shared__ float cs[8][256];
  reinterpret_cast<float4*>(&cs[w][0])[lane] = cacc;
  __syncthreads();
  if (tid < 256) {
    float s = 0.f;
    #pragma unroll
    for (int ww = 0; ww < 8; ++ww) s += cs[ww][tid];
    csp[blk * 256 + tid] = s;   // plain store, distinct address
  }
}

// ---- bandwidth coefficient (1 block x 1024 threads; stream order = visibility) ----
__global__ void bw_kernel(const float* __restrict__ sq, const float* __restrict__ csp,
                          float* __restrict__ coef) {
  int t = threadIdx.x, w = t >> 6, lane = t & 63;
  int col = t & 255, seg = t >> 8;           // 4 segments x 256 columns

  double c = 0.0;
  #pragma unroll 16
  for (int b2 = 0; b2 < 64; ++b2) c += (double)csp[(size_t)(seg * 64 + b2) * 256 + col];
  __shared__ double csl[4][256];
  csl[seg][col] = c;

  double s1 = 0.0;
  #pragma unroll
  for (int i = 0; i < 8; ++i) s1 += (double)sq[t + i * 1024];
  #pragma unroll
  for (int o = 32; o; o >>= 1) s1 += __shfl_down(s1, o, 64);
  __shared__ double rs[16];
  if (lane == 0) rs[w] = s1;
  __syncthreads();

  double S2p = 0.0;
  if (t < 256) {
    double cc = csl[0][t] + csl[1][t] + csl[2][t] + csl[3][t];
    S2p = cc * cc;
  }
  #pragma unroll
  for (int o = 32; o; o >>= 1) S2p += __shfl_down(S2p, o, 64);
  __shared__ double rs2[4];
  if (t < 256 && lane == 0) rs2[w] = S2p;
  __syncthreads();

  if (t == 0) {
    double S1 = 0.0;
    #pragma unroll
    for (int i = 0; i < 16; ++i) S1 += rs[i];
    double S2 = rs2[0] + rs2[1] + rs2[2] + rs2[3];
    double S  = 2.0 * (double)N_TOT * S1 - 2.0 * S2;   // sum of all pairwise sq dists
    double bw = (S / ((double)N_TOT * (double)N_TOT - (double)N_TOT)) / 4.0;
    *coef = (float)(-1.4426950408889634 / (16.0 * bw));
  }
}

// ---- fused gram + RBF epilogue: 512 blocks x 4-5 tiles, all-direct-L2, no LDS ----
__launch_bounds__(256, 2)
__global__ void gram_kernel(const unsigned short* __restrict__ Xbt, const float* __restrict__ sq,
                            const float* __restrict__ coefp, double* __restrict__ partial) {
  int tid = threadIdx.x;
  int w = tid >> 6, lane = tid & 63;
  const int lo = lane & 15, hi = lane >> 4;
  const int wr = w >> 1, wc = w & 1;
  const int fragoff = hi * 256 + lo * 16;

  // XCD-contiguous swizzle (512 % 8 == 0): XCD c gets blocks [c*64, (c+1)*64)
  int orig = (int)blockIdx.x;
  int blk  = (orig & 7) * (NBLK / 8) + (orig >> 3);

  // 2080 tiles -> blocks 0..31 get 5 consecutive tiles, 32..511 get 4
  int first, ntl;
  if (blk < 32) { first = blk * 5; ntl = 5; }
  else          { first = 160 + (blk - 32) * 4; ntl = 4; }

  // row-major upper-tri decode of first tile: row bi has (64-bi) tiles
  int bi = 0, rem = first;
  while (rem >= NB - bi) { rem -= NB - bi; ++bi; }
  int bj = bi + rem;

  const char* Xb = (const char*)Xbt;
  float coef = *coefp;
  double dsum = 0.0;

  for (int t = 0; t < ntl; ++t) {
    float factor = ((bi < 32) == (bj < 32)) ? 1.f : -1.f;
    if (bi != bj) factor *= 2.f;

    const char* pA = Xb + (size_t)(bi * 8 + wr * 4) * 8192 + fragoff;
    const char* pB = Xb + (size_t)(bj * 8 + wc * 4) * 8192 + fragoff;

    f32x4 acc[4][4];
    #pragma unroll
    for (int m = 0; m < 4; ++m)
      #pragma unroll
      for (int n = 0; n < 4; ++n) acc[m][n] = (f32x4){0.f, 0.f, 0.f, 0.f};

    // forced pipeline, all from L2: B 4-deep ring (16 outstanding 1KB loads),
    // A 2-deep ring. R13 slot discipline: A slots disjoint (prefetch early);
    // B prefetch AFTER the MFMA cluster that last reads the slot.
    bf16x8 b[4][4], a[2][4];
    #pragma unroll
    for (int s = 0; s < 4; ++s)
      #pragma unroll
      for (int n = 0; n < 4; ++n)
        b[s][n] = *(const bf16x8*)(pB + n * 8192 + s * 1024);
    #pragma unroll
    for (int m = 0; m < 4; ++m) a[0][m] = *(const bf16x8*)(pA + m * 8192);

    #pragma unroll
    for (int kc = 0; kc < 8; ++kc) {
      if (kc + 1 < 8) {                      // A prefetch: disjoint ring slots
        #pragma unroll
        for (int m = 0; m < 4; ++m)
          a[(kc + 1) & 1][m] = *(const bf16x8*)(pA + m * 8192 + (kc + 1) * 1024);
      }
      #pragma unroll
      for (int m = 0; m < 4; ++m)
        #pragma unroll
        for (int n = 0; n < 4; ++n)
          acc[m][n] = __builtin_amdgcn_mfma_f32_16x16x32_bf16(a[kc & 1][m], b[kc & 3][n],
                                                              acc[m][n], 0, 0, 0);
      if (kc + 4 < 8) {                      // B prefetch AFTER last read of slot kc&3
        #pragma unroll
        for (int n = 0; n < 4; ++n)
          b[kc & 3][n] = *(const bf16x8*)(pB + n * 8192 + (kc + 4) * 1024);
      }
    }

    // epilogue: d2 = max(sq_i+sq_j-2g, 0); kernels = u+u^2+u^4+u^8+u^16, u=exp2(d2*coef)
    float sqj[4], sqi[4][4];
    #pragma unroll
    for (int n = 0; n < 4; ++n) sqj[n] = sq[bj * 128 + wc * 64 + n * 16 + lo];
    #pragma unroll
    for (int m = 0; m < 4; ++m)
      #pragma unroll
      for (int r = 0; r < 4; ++r) sqi[m][r] = sq[bi * 128 + wr * 64 + m * 16 + hi * 4 + r];

    float psum = 0.f;
    #pragma unroll
    for (int m = 0; m < 4; ++m) {
      #pragma unroll
      for (int n = 0; n < 4; ++n) {
        #pragma unroll
        for (int r = 0; r < 4; ++r) {
          float g  = acc[m][n][r];
          float d2 = fmaxf(fmaf(-2.f, g, sqi[m][r] + sqj[n]), 0.f);
          float u  = __builtin_amdgcn_exp2f(d2 * coef);
          float u2 = u * u, u4 = u2 * u2, u8 = u4 * u4, u16 = u8 * u8;
          psum += (u + u2) + (u4 + u8) + u16;
        }
      }
    }
    #pragma unroll
    for (int o = 32; o; o >>= 1) psum += __shfl_down(psum, o, 64);
    if (lane == 0) dsum += (double)(psum * factor);

    // advance to next consecutive tile
    ++bj;
    if (bj == NB) { ++bi; bj = bi; }
  }

  __shared__ double wred[4];
  if (lane == 0) wred[w] = dsum;
  __syncthreads();
  if (tid == 0)
    partial[blk] = wred[0] + wred[1] + wred[2] + wred[3];   // plain store
}

// ---- final reduction (1 block; stream order = visibility) ----
__global__ void reduce_kernel(const double* __restrict__ partial, float* __restrict__ out) {
  int t = threadIdx.x, w = t >> 6, lane = t & 63;
  double s = 0.0;
  for (int i = t; i < NBLK; i += 256) s += partial[i];
  #pragma unroll
  for (int o = 32; o; o >>= 1) s += __shfl_down(s, o, 64);
  __shared__ double rs[4];
  if (lane == 0) rs[w] = s;
  __syncthreads();
  if (t == 0)
    out[0] = (float)((rs[0] + rs[1] + rs[2] + rs[3]) / ((double)BS * (double)BS));
}

extern "C" void kernel_launch(void* const* d_in, const int* in_sizes, int n_in,
                              void* d_out, int out_size, void* d_ws, size_t ws_size,
                              hipStream_t stream) {
  const float* src = (const float*)d_in[0];
  const float* tgt = (const float*)d_in[1];
  char* ws = (char*)d_ws;
  float*  coef    = (float*)(ws + 0);
  double* partial = (double*)(ws + 64);
  float*  csp     = (float*)(ws + 16704);
  float*  sq      = (float*)(ws + 278848);
  unsigned short* Xbt = (unsigned short*)(ws + 311616);
  float* out = (float*)d_out;

  prep_kernel<<<256, 512, 0, stream>>>(src, tgt, Xbt, sq, csp);
  bw_kernel<<<1, 1024, 0, stream>>>(sq, csp, coef);
  gram_kernel<<<NBLK, 256, 0, stream>>>(Xbt, sq, coef, partial);
  reduce_kernel<<<1, 256, 0, stream>>>(partial, out);
}

// Round 17
// 53.872 us; speedup vs baseline: 1.1563x; 1.1563x over previous
//
#include <hip/hip_runtime.h>
#include <stdint.h>
#include <stddef.h>

// MMD loss, fused: gram = X·X^T (bf16 MFMA) + 5-kernel RBF epilogue + signed mean.
// N=8192 rows (4096 src + 4096 tgt), D=256.
//
// Round-17 = Round-16 with the register cap REMOVED (__launch_bounds__(256,1)).
//  R16 evidence: VGPR_Count=128 + WRITE_SIZE 4.1MB (8KB/block scratch) + FETCH
//  +4.9MB -> the no-LDS config spilled under the compiler's 128-reg choice and
//  never tested the actual hypothesis. Live set ~190 regs (64 acc + 64 B-ring
//  + 32 A-ring + addr) fits 512 cap; ~200x8 waves = 1600 < 2048 VGPR pool ->
//  residency stays 2 blocks/CU (same as R13), isolating the spill variable.
//  Hypothesis: freeing the per-CU LDS pipe (R13: 256 ds_read_b128/tile/CU @
//  ~12cyc serialized) onto the 5%-utilized vector-memory path cuts the
//  per-tile serial chain.
//  Kept: zero device-scope serialization, plain-store partials, 512 blocks x
//  4-5 consecutive tiles, XCD swizzle, fragment-transposed Xbt, R13 ring
//  discipline (A slots disjoint; B prefetch after last read of its slot).
//
// Fragment layout: elem(r,k) at (r>>4)*4096 + (k>>3)*128 + (r&15)*8 + (k&7)
// -> lane(lo,hi) fragment base byte = rowgroup*8192 + (kc*4+hi)*256 + lo*16
//    (contiguous 1KB per wave per fragment load).
//
// ws layout:
//   [0]      float  coef            (-log2(e)/(16*bandwidth))
//   [64]     double partial[512]    -> [64, 4160)
//   [16704]  float  csp[256*256]    -> [16704, 278848)
//   [278848] float  sq[8192]        -> [278848, 311616)
//   [311616] ushort Xbt[8192*256]   (bf16, fragment-transposed, 4MB)

#define N_TOT 8192
#define D_DIM 256
#define BS    4096
#define NB    64      // 128-row tiles per dim
#define NTILE 2080    // upper-tri 128x128 tiles
#define NBLK  512     // blocks: 32 x 5 tiles + 480 x 4 tiles = 2080 (% 8 == 0)

typedef float  f32x4  __attribute__((ext_vector_type(4)));
typedef short  bf16x8 __attribute__((ext_vector_type(8)));

__device__ __forceinline__ unsigned short f2bf(float f) {
  unsigned u = __float_as_uint(f);
  u += 0x7fffu + ((u >> 16) & 1u);   // RNE; inputs are finite
  return (unsigned short)(u >> 16);
}
__device__ __forceinline__ float bf2f(unsigned short s) {
  return __uint_as_float(((unsigned)s) << 16);
}

// ---- prep: f32 -> bf16 fragment-transposed copy + row sq-norms + column partials ----
// 256 blocks x 512 threads; 32 rows/block, 4 rows/wave.
__global__ void prep_kernel(const float* __restrict__ src, const float* __restrict__ tgt,
                            unsigned short* __restrict__ Xbt, float* __restrict__ sq,
                            float* __restrict__ csp) {
  int tid  = threadIdx.x;
  int w    = tid >> 6, lane = tid & 63;
  int blk  = blockIdx.x;
  float4 cacc = {0.f, 0.f, 0.f, 0.f};

  #pragma unroll
  for (int r = 0; r < 4; ++r) {
    int row = blk * 32 + w * 4 + r;
    const float* rowp = (row < BS) ? (src + (size_t)row * D_DIM)
                                   : (tgt + (size_t)(row - BS) * D_DIM);
    float4 v = reinterpret_cast<const float4*>(rowp)[lane];   // cols k..k+3, k=lane*4
    cacc.x += v.x; cacc.y += v.y; cacc.z += v.z; cacc.w += v.w;
    ushort4 b;
    b.x = f2bf(v.x); b.y = f2bf(v.y); b.z = f2bf(v.z); b.w = f2bf(v.w);
    int k = lane * 4;
    size_t off = ((size_t)(row >> 4)) * 4096 + (size_t)(k >> 3) * 128
               + (size_t)((row & 15) * 8) + (k & 7);
    *reinterpret_cast<ushort4*>(Xbt + off) = b;
    float fx = bf2f(b.x), fy = bf2f(b.y), fz = bf2f(b.z), fw = bf2f(b.w);
    float s = fx * fx + fy * fy + fz * fz + fw * fw;
    #pragma unroll
    for (int o = 32; o; o >>= 1) s += __shfl_down(s, o, 64);
    if (lane == 0) sq[row] = s;
  }

  __shared__ float cs[8][256];
  reinterpret_cast<float4*>(&cs[w][0])[lane] = cacc;
  __syncthreads();
  if (tid < 256) {
    float s = 0.f;
    #pragma unroll
    for (int ww = 0; ww < 8; ++ww) s += cs[ww][tid];
    csp[blk * 256 + tid] = s;   // plain store, distinct address
  }
}

// ---- bandwidth coefficient (1 block x 1024 threads; stream order = visibility) ----
__global__ void bw_kernel(const float* __restrict__ sq, const float* __restrict__ csp,
                          float* __restrict__ coef) {
  int t = threadIdx.x, w = t >> 6, lane = t & 63;
  int col = t & 255, seg = t >> 8;           // 4 segments x 256 columns

  double c = 0.0;
  #pragma unroll 16
  for (int b2 = 0; b2 < 64; ++b2) c += (double)csp[(size_t)(seg * 64 + b2) * 256 + col];
  __shared__ double csl[4][256];
  csl[seg][col] = c;

  double s1 = 0.0;
  #pragma unroll
  for (int i = 0; i < 8; ++i) s1 += (double)sq[t + i * 1024];
  #pragma unroll
  for (int o = 32; o; o >>= 1) s1 += __shfl_down(s1, o, 64);
  __shared__ double rs[16];
  if (lane == 0) rs[w] = s1;
  __syncthreads();

  double S2p = 0.0;
  if (t < 256) {
    double cc = csl[0][t] + csl[1][t] + csl[2][t] + csl[3][t];
    S2p = cc * cc;
  }
  #pragma unroll
  for (int o = 32; o; o >>= 1) S2p += __shfl_down(S2p, o, 64);
  __shared__ double rs2[4];
  if (t < 256 && lane == 0) rs2[w] = S2p;
  __syncthreads();

  if (t == 0) {
    double S1 = 0.0;
    #pragma unroll
    for (int i = 0; i < 16; ++i) S1 += rs[i];
    double S2 = rs2[0] + rs2[1] + rs2[2] + rs2[3];
    double S  = 2.0 * (double)N_TOT * S1 - 2.0 * S2;   // sum of all pairwise sq dists
    double bw = (S / ((double)N_TOT * (double)N_TOT - (double)N_TOT)) / 4.0;
    *coef = (float)(-1.4426950408889634 / (16.0 * bw));
  }
}

// ---- fused gram + RBF epilogue: 512 blocks x 4-5 tiles, all-direct-L2, no LDS ----
__launch_bounds__(256, 1)
__global__ void gram_kernel(const unsigned short* __restrict__ Xbt, const float* __restrict__ sq,
                            const float* __restrict__ coefp, double* __restrict__ partial) {
  int tid = threadIdx.x;
  int w = tid >> 6, lane = tid & 63;
  const int lo = lane & 15, hi = lane >> 4;
  const int wr = w >> 1, wc = w & 1;
  const int fragoff = hi * 256 + lo * 16;

  // XCD-contiguous swizzle (512 % 8 == 0): XCD c gets blocks [c*64, (c+1)*64)
  int orig = (int)blockIdx.x;
  int blk  = (orig & 7) * (NBLK / 8) + (orig >> 3);

  // 2080 tiles -> blocks 0..31 get 5 consecutive tiles, 32..511 get 4
  int first, ntl;
  if (blk < 32) { first = blk * 5; ntl = 5; }
  else          { first = 160 + (blk - 32) * 4; ntl = 4; }

  // row-major upper-tri decode of first tile: row bi has (64-bi) tiles
  int bi = 0, rem = first;
  while (rem >= NB - bi) { rem -= NB - bi; ++bi; }
  int bj = bi + rem;

  const char* Xb = (const char*)Xbt;
  float coef = *coefp;
  double dsum = 0.0;

  for (int t = 0; t < ntl; ++t) {
    float factor = ((bi < 32) == (bj < 32)) ? 1.f : -1.f;
    if (bi != bj) factor *= 2.f;

    const char* pA = Xb + (size_t)(bi * 8 + wr * 4) * 8192 + fragoff;
    const char* pB = Xb + (size_t)(bj * 8 + wc * 4) * 8192 + fragoff;

    f32x4 acc[4][4];
    #pragma unroll
    for (int m = 0; m < 4; ++m)
      #pragma unroll
      for (int n = 0; n < 4; ++n) acc[m][n] = (f32x4){0.f, 0.f, 0.f, 0.f};

    // forced pipeline, all from L2: B 4-deep ring (16 outstanding 1KB loads),
    // A 2-deep ring. R13 slot discipline: A slots disjoint (prefetch early);
    // B prefetch AFTER the MFMA cluster that last reads the slot.
    bf16x8 b[4][4], a[2][4];
    #pragma unroll
    for (int s = 0; s < 4; ++s)
      #pragma unroll
      for (int n = 0; n < 4; ++n)
        b[s][n] = *(const bf16x8*)(pB + n * 8192 + s * 1024);
    #pragma unroll
    for (int m = 0; m < 4; ++m) a[0][m] = *(const bf16x8*)(pA + m * 8192);

    #pragma unroll
    for (int kc = 0; kc < 8; ++kc) {
      if (kc + 1 < 8) {                      // A prefetch: disjoint ring slots
        #pragma unroll
        for (int m = 0; m < 4; ++m)
          a[(kc + 1) & 1][m] = *(const bf16x8*)(pA + m * 8192 + (kc + 1) * 1024);
      }
      #pragma unroll
      for (int m = 0; m < 4; ++m)
        #pragma unroll
        for (int n = 0; n < 4; ++n)
          acc[m][n] = __builtin_amdgcn_mfma_f32_16x16x32_bf16(a[kc & 1][m], b[kc & 3][n],
                                                              acc[m][n], 0, 0, 0);
      if (kc + 4 < 8) {                      // B prefetch AFTER last read of slot kc&3
        #pragma unroll
        for (int n = 0; n < 4; ++n)
          b[kc & 3][n] = *(const bf16x8*)(pB + n * 8192 + (kc + 4) * 1024);
      }
    }

    // epilogue: d2 = max(sq_i+sq_j-2g, 0); kernels = u+u^2+u^4+u^8+u^16, u=exp2(d2*coef)
    float sqj[4], sqi[4][4];
    #pragma unroll
    for (int n = 0; n < 4; ++n) sqj[n] = sq[bj * 128 + wc * 64 + n * 16 + lo];
    #pragma unroll
    for (int m = 0; m < 4; ++m)
      #pragma unroll
      for (int r = 0; r < 4; ++r) sqi[m][r] = sq[bi * 128 + wr * 64 + m * 16 + hi * 4 + r];

    float psum = 0.f;
    #pragma unroll
    for (int m = 0; m < 4; ++m) {
      #pragma unroll
      for (int n = 0; n < 4; ++n) {
        #pragma unroll
        for (int r = 0; r < 4; ++r) {
          float g  = acc[m][n][r];
          float d2 = fmaxf(fmaf(-2.f, g, sqi[m][r] + sqj[n]), 0.f);
          float u  = __builtin_amdgcn_exp2f(d2 * coef);
          float u2 = u * u, u4 = u2 * u2, u8 = u4 * u4, u16 = u8 * u8;
          psum += (u + u2) + (u4 + u8) + u16;
        }
      }
    }
    #pragma unroll
    for (int o = 32; o; o >>= 1) psum += __shfl_down(psum, o, 64);
    if (lane == 0) dsum += (double)(psum * factor);

    // advance to next consecutive tile
    ++bj;
    if (bj == NB) { ++bi; bj = bi; }
  }

  __shared__ double wred[4];
  if (lane == 0) wred[w] = dsum;
  __syncthreads();
  if (tid == 0)
    partial[blk] = wred[0] + wred[1] + wred[2] + wred[3];   // plain store
}

// ---- final reduction (1 block; stream order = visibility) ----
__global__ void reduce_kernel(const double* __restrict__ partial, float* __restrict__ out) {
  int t = threadIdx.x, w = t >> 6, lane = t & 63;
  double s = 0.0;
  for (int i = t; i < NBLK; i += 256) s += partial[i];
  #pragma unroll
  for (int o = 32; o; o >>= 1) s += __shfl_down(s, o, 64);
  __shared__ double rs[4];
  if (lane == 0) rs[w] = s;
  __syncthreads();
  if (t == 0)
    out[0] = (float)((rs[0] + rs[1] + rs[2] + rs[3]) / ((double)BS * (double)BS));
}

extern "C" void kernel_launch(void* const* d_in, const int* in_sizes, int n_in,
                              void* d_out, int out_size, void* d_ws, size_t ws_size,
                              hipStream_t stream) {
  const float* src = (const float*)d_in[0];
  const float* tgt = (const float*)d_in[1];
  char* ws = (char*)d_ws;
  float*  coef    = (float*)(ws + 0);
  double* partial = (double*)(ws + 64);
  float*  csp     = (float*)(ws + 16704);
  float*  sq      = (float*)(ws + 278848);
  unsigned short* Xbt = (unsigned short*)(ws + 311616);
  float* out = (float*)d_out;

  prep_kernel<<<256, 512, 0, stream>>>(src, tgt, Xbt, sq, csp);
  bw_kernel<<<1, 1024, 0, stream>>>(sq, csp, coef);
  gram_kernel<<<NBLK, 256, 0, stream>>>(Xbt, sq, coef, partial);
  reduce_kernel<<<1, 256, 0, stream>>>(partial, out);
}

// Round 18
// 47.422 us; speedup vs baseline: 1.3136x; 1.1360x over previous
//
#include <hip/hip_runtime.h>
#include <stdint.h>
#include <stddef.h>

// MMD loss, fused: gram = X·X^T (bf16 MFMA) + 5-kernel RBF epilogue + signed mean.
// N=8192 rows (4096 src + 4096 tgt), D=256.
//
// Round-18 = best-of composition: R14's gram (best measured, ~32us: LDS A
// panel staged on row change + continuous cross-tile 4-deep B-ring, (256,2),
// 512 blocks x 4-5 consecutive tiles) + R17's parallel 1024-thread bw_kernel
// (R14 still had the serial 256-iter bw loop).
//  Experiment matrix closed: coalescing(R4)=0, locality(R5)=0,
//  serialization(R7)=BIG, spill(R9/R16)=neutral/neg, block count(R11)=0,
//  forced ring pipeline(R13)=WIN, cross-tile prefetch(R14)=0, 2xTLP(R15)=neg,
//  no-LDS(R17)=neg. Residual gram gap (~32us vs ~13us floor, MfmaUtil ~15%)
//  is the per-wave chain/contention regime; past it needs inline-asm counted
//  vmcnt scheduling (guide §5), out of scope here.
//
// Fragment layout: elem(r,k) at (r>>4)*4096 + (k>>3)*128 + (r&15)*8 + (k&7)
// -> lane(lo,hi) fragment base byte = rowgroup*8192 + (kc*4+hi)*256 + lo*16
//    (contiguous 1KB per wave per fragment; A panel = 64KB contiguous).
//
// ws layout:
//   [0]      float  coef            (-log2(e)/(16*bandwidth))
//   [64]     double partial[512]    -> [64, 4160)
//   [16704]  float  csp[256*256]    -> [16704, 278848)
//   [278848] float  sq[8192]        -> [278848, 311616)
//   [311616] ushort Xbt[8192*256]   (bf16, fragment-transposed, 4MB)

#define N_TOT 8192
#define D_DIM 256
#define BS    4096
#define NB    64      // 128-row tiles per dim
#define NTILE 2080    // upper-tri 128x128 tiles
#define NBLK  512     // blocks: 32 x 5 tiles + 480 x 4 tiles = 2080 (% 8 == 0)

typedef float  f32x4  __attribute__((ext_vector_type(4)));
typedef short  bf16x8 __attribute__((ext_vector_type(8)));

typedef __attribute__((address_space(1))) const unsigned int gas_u32;
typedef __attribute__((address_space(3))) unsigned int       lds_u32;

__device__ __forceinline__ unsigned short f2bf(float f) {
  unsigned u = __float_as_uint(f);
  u += 0x7fffu + ((u >> 16) & 1u);   // RNE; inputs are finite
  return (unsigned short)(u >> 16);
}
__device__ __forceinline__ float bf2f(unsigned short s) {
  return __uint_as_float(((unsigned)s) << 16);
}

// ---- prep: f32 -> bf16 fragment-transposed copy + row sq-norms + column partials ----
// 256 blocks x 512 threads; 32 rows/block, 4 rows/wave.
__global__ void prep_kernel(const float* __restrict__ src, const float* __restrict__ tgt,
                            unsigned short* __restrict__ Xbt, float* __restrict__ sq,
                            float* __restrict__ csp) {
  int tid  = threadIdx.x;
  int w    = tid >> 6, lane = tid & 63;
  int blk  = blockIdx.x;
  float4 cacc = {0.f, 0.f, 0.f, 0.f};

  #pragma unroll
  for (int r = 0; r < 4; ++r) {
    int row = blk * 32 + w * 4 + r;
    const float* rowp = (row < BS) ? (src + (size_t)row * D_DIM)
                                   : (tgt + (size_t)(row - BS) * D_DIM);
    float4 v = reinterpret_cast<const float4*>(rowp)[lane];   // cols k..k+3, k=lane*4
    cacc.x += v.x; cacc.y += v.y; cacc.z += v.z; cacc.w += v.w;
    ushort4 b;
    b.x = f2bf(v.x); b.y = f2bf(v.y); b.z = f2bf(v.z); b.w = f2bf(v.w);
    int k = lane * 4;
    size_t off = ((size_t)(row >> 4)) * 4096 + (size_t)(k >> 3) * 128
               + (size_t)((row & 15) * 8) + (k & 7);
    *reinterpret_cast<ushort4*>(Xbt + off) = b;
    float fx = bf2f(b.x), fy = bf2f(b.y), fz = bf2f(b.z), fw = bf2f(b.w);
    float s = fx * fx + fy * fy + fz * fz + fw * fw;
    #pragma unroll
    for (int o = 32; o; o >>= 1) s += __shfl_down(s, o, 64);
    if (lane == 0) sq[row] = s;
  }

  __shared__ float cs[8][256];
  reinterpret_cast<float4*>(&cs[w][0])[lane] = cacc;
  __syncthreads();
  if (tid < 256) {
    float s = 0.f;
    #pragma unroll
    for (int ww = 0; ww < 8; ++ww) s += cs[ww][tid];
    csp[blk * 256 + tid] = s;   // plain store, distinct address
  }
}

// ---- bandwidth coefficient (1 block x 1024 threads; stream order = visibility) ----
__global__ void bw_kernel(const float* __restrict__ sq, const float* __restrict__ csp,
                          float* __restrict__ coef) {
  int t = threadIdx.x, w = t >> 6, lane = t & 63;
  int col = t & 255, seg = t >> 8;           // 4 segments x 256 columns

  double c = 0.0;
  #pragma unroll 16
  for (int b2 = 0; b2 < 64; ++b2) c += (double)csp[(size_t)(seg * 64 + b2) * 256 + col];
  __shared__ double csl[4][256];
  csl[seg][col] = c;

  double s1 = 0.0;
  #pragma unroll
  for (int i = 0; i < 8; ++i) s1 += (double)sq[t + i * 1024];
  #pragma unroll
  for (int o = 32; o; o >>= 1) s1 += __shfl_down(s1, o, 64);
  __shared__ double rs[16];
  if (lane == 0) rs[w] = s1;
  __syncthreads();

  double S2p = 0.0;
  if (t < 256) {
    double cc = csl[0][t] + csl[1][t] + csl[2][t] + csl[3][t];
    S2p = cc * cc;
  }
  #pragma unroll
  for (int o = 32; o; o >>= 1) S2p += __shfl_down(S2p, o, 64);
  __shared__ double rs2[4];
  if (t < 256 && lane == 0) rs2[w] = S2p;
  __syncthreads();

  if (t == 0) {
    double S1 = 0.0;
    #pragma unroll
    for (int i = 0; i < 16; ++i) S1 += rs[i];
    double S2 = rs2[0] + rs2[1] + rs2[2] + rs2[3];
    double S  = 2.0 * (double)N_TOT * S1 - 2.0 * S2;   // sum of all pairwise sq dists
    double bw = (S / ((double)N_TOT * (double)N_TOT - (double)N_TOT)) / 4.0;
    *coef = (float)(-1.4426950408889634 / (16.0 * bw));
  }
}

// ---- fused gram + RBF epilogue: 512 blocks x 4-5 tiles, continuous B pipeline ----
__launch_bounds__(256, 2)
__global__ void gram_kernel(const unsigned short* __restrict__ Xbt, const float* __restrict__ sq,
                            const float* __restrict__ coefp, double* __restrict__ partial) {
  __shared__ __align__(16) unsigned char Alds[65536];   // full 128x256 A panel

  int tid = threadIdx.x;
  int w = tid >> 6, lane = tid & 63;
  const int lo = lane & 15, hi = lane >> 4;
  const int wr = w >> 1, wc = w & 1;

  // XCD-contiguous swizzle (512 % 8 == 0): XCD c gets blocks [c*64, (c+1)*64)
  int orig = (int)blockIdx.x;
  int blk  = (orig & 7) * (NBLK / 8) + (orig >> 3);

  // 2080 tiles -> blocks 0..31 get 5 consecutive tiles, 32..511 get 4
  int first, ntl;
  if (blk < 32) { first = blk * 5; ntl = 5; }
  else          { first = 160 + (blk - 32) * 4; ntl = 4; }

  // row-major upper-tri decode of first tile: row bi has (64-bi) tiles
  int bi = 0, rem = first;
  while (rem >= NB - bi) { rem -= NB - bi; ++bi; }
  int bj = bi + rem;

  const char* Xb = (const char*)Xbt;
  float coef = *coefp;
  int bi_staged = -1;
  double dsum = 0.0;

  const int fragoff = hi * 256 + lo * 16;
  const char* pB = Xb + (size_t)(bj * 8 + wc * 4) * 8192 + fragoff;

  // persistent B ring: preload first tile's 4 chunks (16 outstanding 1KB loads)
  bf16x8 b[4][4], a[2][4];
  #pragma unroll
  for (int s = 0; s < 4; ++s)
    #pragma unroll
    for (int n = 0; n < 4; ++n)
      b[s][n] = *(const bf16x8*)(pB + n * 8192 + s * 1024);

  for (int t = 0; t < ntl; ++t) {
    // stage A panel on row change (64KB identity copy; block-uniform branch)
    if (bi != bi_staged) {
      __syncthreads();                       // all waves done reading old A
      const char* srcA = Xb + (size_t)bi * 65536 + w * 16384 + lane * 16;
      unsigned char* dstA = Alds + w * 16384;
      #pragma unroll
      for (int i = 0; i < 16; ++i)
        __builtin_amdgcn_global_load_lds((gas_u32*)(srcA + i * 1024),
                                         (lds_u32*)(dstA + i * 1024), 16, 0, 0);
      __syncthreads();                       // compiler drains vmcnt before barrier
      bi_staged = bi;
    }

    float factor = ((bi < 32) == (bj < 32)) ? 1.f : -1.f;
    if (bi != bj) factor *= 2.f;

    // next-tile B base (clamped at the global last tile; duplicate loads harmless)
    int nbi = bi, nbj = bj + 1;
    if (nbj == NB) { ++nbi; nbj = nbi; }
    if (nbi >= NB) { nbi = bi; nbj = bj; }
    const char* pBn = Xb + (size_t)(nbj * 8 + wc * 4) * 8192 + fragoff;

    const char* pAl = (const char*)Alds + (size_t)(wr * 4) * 8192 + fragoff;

    f32x4 acc[4][4];
    #pragma unroll
    for (int m = 0; m < 4; ++m)
      #pragma unroll
      for (int n = 0; n < 4; ++n) acc[m][n] = (f32x4){0.f, 0.f, 0.f, 0.f};

    #pragma unroll
    for (int m = 0; m < 4; ++m) a[0][m] = *(const bf16x8*)(pAl + m * 8192);

    #pragma unroll
    for (int kc = 0; kc < 8; ++kc) {
      if (kc + 1 < 8) {                      // A prefetch: disjoint slots
        #pragma unroll
        for (int m = 0; m < 4; ++m)
          a[(kc + 1) & 1][m] = *(const bf16x8*)(pAl + m * 8192 + (kc + 1) * 1024);
      }
      #pragma unroll
      for (int m = 0; m < 4; ++m)
        #pragma unroll
        for (int n = 0; n < 4; ++n)
          acc[m][n] = __builtin_amdgcn_mfma_f32_16x16x32_bf16(a[kc & 1][m], b[kc & 3][n],
                                                              acc[m][n], 0, 0, 0);
      // B prefetch AFTER last read of slot kc&3:
      //  kc=0..3 -> this tile's chunks 4..7; kc=4..7 -> NEXT tile's chunks 0..3
      if (kc + 4 < 8) {
        #pragma unroll
        for (int n = 0; n < 4; ++n)
          b[kc & 3][n] = *(const bf16x8*)(pB + n * 8192 + (kc + 4) * 1024);
      } else {
        #pragma unroll
        for (int n = 0; n < 4; ++n)
          b[kc & 3][n] = *(const bf16x8*)(pBn + n * 8192 + (kc - 4) * 1024);
      }
    }

    // epilogue: d2 = max(sq_i+sq_j-2g, 0); kernels = u+u^2+u^4+u^8+u^16, u=exp2(d2*coef)
    // (runs while next tile's B loads are in flight)
    float sqj[4], sqi[4][4];
    #pragma unroll
    for (int n = 0; n < 4; ++n) sqj[n] = sq[bj * 128 + wc * 64 + n * 16 + lo];
    #pragma unroll
    for (int m = 0; m < 4; ++m)
      #pragma unroll
      for (int r = 0; r < 4; ++r) sqi[m][r] = sq[bi * 128 + wr * 64 + m * 16 + hi * 4 + r];

    float psum = 0.f;
    #pragma unroll
    for (int m = 0; m < 4; ++m) {
      #pragma unroll
      for (int n = 0; n < 4; ++n) {
        #pragma unroll
        for (int r = 0; r < 4; ++r) {
          float g  = acc[m][n][r];
          float d2 = fmaxf(fmaf(-2.f, g, sqi[m][r] + sqj[n]), 0.f);
          float u  = __builtin_amdgcn_exp2f(d2 * coef);
          float u2 = u * u, u4 = u2 * u2, u8 = u4 * u4, u16 = u8 * u8;
          psum += (u + u2) + (u4 + u8) + u16;
        }
      }
    }
    #pragma unroll
    for (int o = 32; o; o >>= 1) psum += __shfl_down(psum, o, 64);
    if (lane == 0) dsum += (double)(psum * factor);

    // advance to next consecutive tile
    pB = pBn;
    ++bj;
    if (bj == NB) { ++bi; bj = bi; }
  }

  __shared__ double wred[4];
  if (lane == 0) wred[w] = dsum;
  __syncthreads();
  if (tid == 0)
    partial[blk] = wred[0] + wred[1] + wred[2] + wred[3];   // plain store
}

// ---- final reduction (1 block; stream order = visibility) ----
__global__ void reduce_kernel(const double* __restrict__ partial, float* __restrict__ out) {
  int t = threadIdx.x, w = t >> 6, lane = t & 63;
  double s = 0.0;
  for (int i = t; i < NBLK; i += 256) s += partial[i];
  #pragma unroll
  for (int o = 32; o; o >>= 1) s += __shfl_down(s, o, 64);
  __shared__ double rs[4];
  if (lane == 0) rs[w] = s;
  __syncthreads();
  if (t == 0)
    out[0] = (float)((rs[0] + rs[1] + rs[2] + rs[3]) / ((double)BS * (double)BS));
}

extern "C" void kernel_launch(void* const* d_in, const int* in_sizes, int n_in,
                              void* d_out, int out_size, void* d_ws, size_t ws_size,
                              hipStream_t stream) {
  const float* src = (const float*)d_in[0];
  const float* tgt = (const float*)d_in[1];
  char* ws = (char*)d_ws;
  float*  coef    = (float*)(ws + 0);
  double* partial = (double*)(ws + 64);
  float*  csp     = (float*)(ws + 16704);
  float*  sq      = (float*)(ws + 278848);
  unsigned short* Xbt = (unsigned short*)(ws + 311616);
  float* out = (float*)d_out;

  prep_kernel<<<256, 512, 0, stream>>>(src, tgt, Xbt, sq, csp);
  bw_kernel<<<1, 1024, 0, stream>>>(sq, csp, coef);
  gram_kernel<<<NBLK, 256, 0, stream>>>(Xbt, sq, coef, partial);
  reduce_kernel<<<1, 256, 0, stream>>>(partial, out);
}